// Round 4
// baseline (72.674 us; speedup 1.0000x reference)
//
#include <hip/hip_runtime.h>

#define NEG_SLOPE 0.2f

// ws layout (in floats)
#define OFF_U   0        // 3 layers * 256 (u_src[128] | u_dst[128])
#define OFF_WT  1024     // 3 * 16384 (W transposed: WT[d*128+e] = W[e*128+d])
#define OFF_XT  50176    // x~ partials: [b][p][h][d] = 64*16*2*128 floats

__device__ __forceinline__ float lrelu(float z) { return z >= 0.f ? z : NEG_SLOPE * z; }

// ---------------------------------------------------------------------------
// Setup: grid 48 = 3 layers x 16 sub-blocks. LDS-tiled coalesced transpose;
// sub==0 block also computes u vectors (u = a @ W).
__global__ __launch_bounds__(256) void setup_kernel(
    const float* __restrict__ W0, const float* __restrict__ as0, const float* __restrict__ ad0,
    const float* __restrict__ W1, const float* __restrict__ as1, const float* __restrict__ ad1,
    const float* __restrict__ W2, const float* __restrict__ as2, const float* __restrict__ ad2,
    float* __restrict__ ws) {
  __shared__ float tile[8][132];
  const int bid = blockIdx.x;
  const int l = bid >> 4, sub = bid & 15;
  const int tid = threadIdx.x;
  const float* W = (l == 0) ? W0 : (l == 1) ? W1 : W2;
  float* WT = ws + OFF_WT + l * 16384;
  const int e0 = sub * 8;

#pragma unroll
  for (int i = 0; i < 4; ++i) {     // read 8 rows of W, coalesced
    const int idx = i * 256 + tid;
    tile[idx >> 7][idx & 127] = W[(e0 + (idx >> 7)) * 128 + (idx & 127)];
  }
  __syncthreads();
#pragma unroll
  for (int i = 0; i < 4; ++i) {     // write transposed
    const int idx = i * 256 + tid;
    const int d = idx >> 3, j = idx & 7;
    WT[d * 128 + e0 + j] = tile[j][d];
  }
  if (sub == 0) {
    const float* av = (tid < 128) ? ((l == 0) ? as0 : (l == 1) ? as1 : as2)
                                  : ((l == 0) ? ad0 : (l == 1) ? ad1 : ad2);
    const int d = tid & 127;
    float acc = 0.f;
#pragma unroll 8
    for (int e = 0; e < 128; ++e) acc += av[e] * W[e * 128 + d];
    ws[OFF_U + l * 256 + tid] = acc;
  }
}

// ---------------------------------------------------------------------------
// Layer 0: one block per (b, patch p, half h). 128 cols per block, x kept in
// registers (16 x float4/thread). LDS ~11 KB -> residency bound by VGPR only.
// Output: x~ partial (128 floats) per block; GEMV deferred to l12.
__global__ __launch_bounds__(256, 4) void l0_kernel(
    const float* __restrict__ x, const int* __restrict__ lengths,
    const float* __restrict__ uvec, float* __restrict__ xt_out) {
  __shared__ float u_sh[256];
  __shared__ float stp[4][256];      // per-wave s (0..127) / t (128..255) partials
  __shared__ float hal[4][128];      // halo per-d products: s@cA,t@cA,s@cB,t@cB
  __shared__ float hred[4][32];
  __shared__ float sF[132], tF[132]; // index k+2, k = col rel c0 (-2..129)
  __shared__ float am1[132], asf[132], ap1[132];
  __shared__ float w_sh[128];

  const int tid  = threadIdx.x;
  const int bid  = blockIdx.x;
  const int b = bid >> 5;
  const int p = (bid >> 1) & 15;
  const int h = bid & 1;
  const int lane = tid & 63;
  const int wave = tid >> 6;
  const int l32  = lane & 31;
  const int hi32 = lane >> 5;
  const int c0 = h * 128;

  u_sh[tid] = uvec[tid];

  // ---- issue all global loads up front (x stays in registers) ----
  const float* xb = x + ((size_t)b * 128) * 4096 + p * 256 + c0;
  float4 xr[16];
#pragma unroll
  for (int it = 0; it < 16; ++it) {
    const int d = it * 8 + wave * 2 + hi32;
    xr[it] = *(const float4*)(xb + (size_t)d * 4096 + l32 * 4);
  }
  // halo column load (2 cols; grp = tid>>7 selects which)
  const int grp = tid >> 7;
  const int hc = ((h == 0) ? 128 : 126) + grp;     // absolute col in patch
  const int dh = tid & 127;
  const float hv = x[((size_t)b * 128 + dh) * 4096 + p * 256 + hc];

  __syncthreads();   // u_sh ready (also drains loads)

  // ---- s,t dot-product partials (fp32, from registers) ----
  float s0 = 0.f, s1 = 0.f, s2 = 0.f, s3 = 0.f;
  float t0 = 0.f, t1 = 0.f, t2 = 0.f, t3 = 0.f;
#pragma unroll
  for (int it = 0; it < 16; ++it) {
    const int d = it * 8 + wave * 2 + hi32;
    const float us = u_sh[d], ud = u_sh[128 + d];
    const float4 v = xr[it];
    s0 += v.x * us; s1 += v.y * us; s2 += v.z * us; s3 += v.w * us;
    t0 += v.x * ud; t1 += v.y * ud; t2 += v.z * ud; t3 += v.w * ud;
  }
  // halo products
  hal[grp * 2 + 0][dh] = hv * u_sh[dh];
  hal[grp * 2 + 1][dh] = hv * u_sh[128 + dh];

  // fold the two 32-lane halves (different d) together
  s0 += __shfl_xor(s0, 32); s1 += __shfl_xor(s1, 32);
  s2 += __shfl_xor(s2, 32); s3 += __shfl_xor(s3, 32);
  t0 += __shfl_xor(t0, 32); t1 += __shfl_xor(t1, 32);
  t2 += __shfl_xor(t2, 32); t3 += __shfl_xor(t3, 32);
  if (hi32 == 0) {
    const int n4 = l32 * 4;
    stp[wave][n4] = s0; stp[wave][n4 + 1] = s1; stp[wave][n4 + 2] = s2; stp[wave][n4 + 3] = s3;
    stp[wave][128 + n4] = t0; stp[wave][128 + n4 + 1] = t1;
    stp[wave][128 + n4 + 2] = t2; stp[wave][128 + n4 + 3] = t3;
  }
  __syncthreads();

  {   // combine across waves -> sF/tF main range (k = 0..127 -> idx 2..129)
    const float r = stp[0][tid] + stp[1][tid] + stp[2][tid] + stp[3][tid];
    if (tid < 128) sF[tid + 2] = r; else tF[(tid - 128) + 2] = r;
  }
  if (tid < 128) {   // halo fold stage 1: [4][128] -> [4][32]
    const int q = tid >> 5, i = tid & 31;
    hred[q][i] = hal[q][i] + hal[q][32 + i] + hal[q][64 + i] + hal[q][96 + i];
  }
  __syncthreads();

  if (tid < 4) {     // halo fold stage 2 -> scalars
    float a = 0.f;
#pragma unroll
    for (int i = 0; i < 32; ++i) a += hred[tid][i];
    if (h == 0) {    // cA=128 (k=128), cB=129 (k=129)
      if (tid == 0) sF[130] = a;
      else if (tid == 1) tF[130] = a;
      else if (tid == 2) sF[131] = a;
    } else {         // cA=126 (k=-2), cB=127 (k=-1)
      if (tid == 0) sF[0] = a;
      else if (tid == 2) sF[1] = a;
      else if (tid == 3) tF[1] = a;
    }
  }
  __syncthreads();

  const int len = lengths[b];

  if (tid <= 128) {  // attention for dst k in [h?-1:0 .. h?127:128]
    const int k = tid - (h ? 1 : 0);
    const int a = c0 + k;
    const float tj = tF[k + 2];
    const float ls = lrelu(sF[k + 2] + tj);
    const float lm = (a > 0)   ? lrelu(sF[k + 1] + tj) : -1e30f;
    const float lp = (a < 255) ? lrelu(sF[k + 3] + tj) : -1e30f;
    const float mx = fmaxf(ls, fmaxf(lm, lp));
    const float em = (a > 0)   ? __expf(lm - mx) : 0.f;
    const float es = __expf(ls - mx);
    const float ep = (a < 255) ? __expf(lp - mx) : 0.f;
    const float vj = ((p * 256 + a) < len) ? 1.f : 0.f;
    const float sc = vj / (em + es + ep);
    am1[k + 2] = em * sc; asf[k + 2] = es * sc; ap1[k + 2] = ep * sc;
  }
  __syncthreads();

  if (tid < 128) {   // source weights over this block's 128 cols
    const int n = tid;
    const int a = c0 + n;
    float w = asf[n + 2];
    if (a < 255) w += am1[n + 3];
    if (a > 0)   w += ap1[n + 1];
    w_sh[n] = w;
  }
  __syncthreads();

  {   // x~_half[d] = sum over 128 cols of w[n]*x[d][n]; shfl reduce per d
    const float4 wv = *(const float4*)(&w_sh[l32 * 4]);
    float* dst = xt_out + (((size_t)b * 16 + p) * 2 + h) * 128;
#pragma unroll
    for (int it = 0; it < 16; ++it) {
      float a = wv.x * xr[it].x + wv.y * xr[it].y + wv.z * xr[it].z + wv.w * xr[it].w;
      a += __shfl_xor(a, 1);  a += __shfl_xor(a, 2);  a += __shfl_xor(a, 4);
      a += __shfl_xor(a, 8);  a += __shfl_xor(a, 16);
      if (l32 == 0) {
        const int d = it * 8 + wave * 2 + hi32;
        dst[d] = a;
      }
    }
  }
}

// ---------------------------------------------------------------------------
// Fused: feat GEMV (W0) + layer1 + layer2. One block per b, 256 threads.
__global__ __launch_bounds__(256) void l12_kernel(
    const float* __restrict__ xtp, const int* __restrict__ lengths,
    const float* __restrict__ ws,
    const float* __restrict__ b0, const float* __restrict__ b1,
    const float* __restrict__ b2, float* __restrict__ out) {
  __shared__ float xt[16][128];
  __shared__ float pr[2][16][128];
  __shared__ float feat[16][128];
  __shared__ float spt[2][16][16];
  __shared__ float s1[16], t1[16], am[16], asf[16], ap[16], w16[16];
  __shared__ float rc_sh[16];
  __shared__ float x1t[4][128];
  __shared__ float h1[4][128];

  const int tid = threadIdx.x;
  const int b = blockIdx.x;
  const float* WT0 = ws + OFF_WT;
  const float* WT1 = ws + OFF_WT + 16384;
  const float* WT2 = ws + OFF_WT + 32768;
  const float* u1  = ws + OFF_U + 256;
  const int len = lengths[b];

#pragma unroll
  for (int i = 0; i < 8; ++i) {   // combine half-patch partials
    const int pp = i * 2 + (tid >> 7);
    const int d = tid & 127;
    const size_t base = (((size_t)b * 16 + pp) * 2) * 128;
    xt[pp][d] = xtp[base + d] + xtp[base + 128 + d];
  }
  if (tid < 16) {
    const int rem = len - tid * 256;
    const int cnt = rem < 0 ? 0 : (rem > 256 ? 256 : rem);
    rc_sh[tid] = cnt > 0 ? 1.f / (float)cnt : 0.f;
  }
  __syncthreads();

  {   // feat[p][e] = sum_d xt[p][d] * WT0[d*128+e]
    const int e = tid & 127, dhalf = tid >> 7;
    float acc[16];
#pragma unroll
    for (int q = 0; q < 16; ++q) acc[q] = 0.f;
#pragma unroll 4
    for (int k = 0; k < 64; ++k) {
      const int d = dhalf * 64 + k;
      const float wv = WT0[d * 128 + e];
#pragma unroll
      for (int q = 0; q < 16; ++q) acc[q] += xt[q][d] * wv;
    }
#pragma unroll
    for (int q = 0; q < 16; ++q) pr[dhalf][q][e] = acc[q];
  }
  __syncthreads();
  {
    const int e = tid & 127, ph = tid >> 7;
    const float bb = b0[e];
#pragma unroll
    for (int i = 0; i < 8; ++i) {
      const int q = ph * 8 + i;
      const float rcv = rc_sh[q];
      const float f = (pr[0][q][e] + pr[1][q][e]) * rcv + bb;
      feat[q][e] = (rcv == 0.f) ? 0.f : f;
    }
  }
  __syncthreads();

  {   // layer-1 s,t partials
    const int q = tid >> 4, sl = tid & 15;
    float ps = 0.f, pt = 0.f;
#pragma unroll
    for (int k = 0; k < 8; ++k) {
      const int e = sl * 8 + k;
      const float f = feat[q][e];
      ps += f * u1[e];
      pt += f * u1[128 + e];
    }
    spt[0][q][sl] = ps; spt[1][q][sl] = pt;
  }
  __syncthreads();
  if (tid < 32) {
    const int q = tid >> 4, pp = tid & 15;
    float a = 0.f;
#pragma unroll
    for (int i = 0; i < 16; ++i) a += spt[q][pp][i];
    if (q == 0) s1[pp] = a; else t1[pp] = a;
  }
  __syncthreads();
  if (tid < 16) {   // attention within groups of 4
    const int jl = tid & 3;
    const float tj = t1[tid];
    const float ls = lrelu(s1[tid] + tj);
    const float lm = (jl > 0) ? lrelu(s1[tid - 1] + tj) : -1e30f;
    const float lp = (jl < 3) ? lrelu(s1[tid + 1] + tj) : -1e30f;
    const float mx = fmaxf(ls, fmaxf(lm, lp));
    const float em = (jl > 0) ? __expf(lm - mx) : 0.f;
    const float es = __expf(ls - mx);
    const float ep = (jl < 3) ? __expf(lp - mx) : 0.f;
    const float sc = 1.f / (em + es + ep);
    am[tid] = em * sc; asf[tid] = es * sc; ap[tid] = ep * sc;
  }
  __syncthreads();
  if (tid < 16) {
    const int jl = tid & 3;
    float w = asf[tid];
    if (jl < 3) w += am[tid + 1];
    if (jl > 0) w += ap[tid - 1];
    w16[tid] = w;
  }
  __syncthreads();
#pragma unroll
  for (int r = 0; r < 2; ++r) {   // x1t[g][d] = sum_j w*feat
    const int idx = r * 256 + tid;
    const int g = idx >> 7, d = idx & 127;
    x1t[g][d] = w16[g * 4] * feat[g * 4][d] + w16[g * 4 + 1] * feat[g * 4 + 1][d]
              + w16[g * 4 + 2] * feat[g * 4 + 2][d] + w16[g * 4 + 3] * feat[g * 4 + 3][d];
  }
  __syncthreads();
  {   // layer-1 GEMV
    const int e = tid & 127, gh = tid >> 7;
    float a0 = 0.f, a1 = 0.f;
#pragma unroll 8
    for (int d = 0; d < 128; ++d) {
      const float wv = WT1[d * 128 + e];
      a0 += x1t[gh * 2][d] * wv;
      a1 += x1t[gh * 2 + 1][d] * wv;
    }
    h1[gh * 2][e]     = a0 * 0.25f + b1[e];
    h1[gh * 2 + 1][e] = a1 * 0.25f + b1[e];
  }
  __syncthreads();
  {   // layer-2 GEMV + output
    const int e = tid & 127, gh = tid >> 7;
    float a0 = 0.f, a1 = 0.f;
#pragma unroll 8
    for (int d = 0; d < 128; ++d) {
      const float wv = WT2[d * 128 + e];
      a0 += h1[gh * 2][d] * wv;
      a1 += h1[gh * 2 + 1][d] * wv;
    }
    const float bb = b2[e];
    out[((size_t)b * 128 + e) * 4 + gh * 2]     = a0 + bb;
    out[((size_t)b * 128 + e) * 4 + gh * 2 + 1] = a1 + bb;
  }
}

// ---------------------------------------------------------------------------
extern "C" void kernel_launch(void* const* d_in, const int* in_sizes, int n_in,
                              void* d_out, int out_size, void* d_ws, size_t ws_size,
                              hipStream_t stream) {
  (void)in_sizes; (void)n_in; (void)out_size; (void)ws_size;
  const float* x       = (const float*)d_in[0];
  const int*   lengths = (const int*)  d_in[1];
  const float* W0  = (const float*)d_in[2];
  const float* as0 = (const float*)d_in[3];
  const float* ad0 = (const float*)d_in[4];
  const float* b0  = (const float*)d_in[5];
  const float* W1  = (const float*)d_in[6];
  const float* as1 = (const float*)d_in[7];
  const float* ad1 = (const float*)d_in[8];
  const float* b1  = (const float*)d_in[9];
  const float* W2  = (const float*)d_in[10];
  const float* as2 = (const float*)d_in[11];
  const float* ad2 = (const float*)d_in[12];
  const float* b2  = (const float*)d_in[13];
  float* ws  = (float*)d_ws;
  float* out = (float*)d_out;

  setup_kernel<<<48, 256, 0, stream>>>(W0, as0, ad0, W1, as1, ad1, W2, as2, ad2, ws);
  l0_kernel<<<2048, 256, 0, stream>>>(x, lengths, ws + OFF_U, ws + OFF_XT);
  l12_kernel<<<64, 256, 0, stream>>>(ws + OFF_XT, lengths, ws, b0, b1, b2, out);
}

// Round 6
// 69.739 us; speedup vs baseline: 1.0421x; 1.0421x over previous
//
#include <hip/hip_runtime.h>

#define NEG_SLOPE 0.2f

// ws layout (in floats)
#define OFF_U   0        // 3 layers * 256 (u_src[128] | u_dst[128])
#define OFF_WT  1024     // 3 * 16384 (W transposed: WT[d*128+e] = W[e*128+d])
#define OFF_XT  50176    // x~ partials: [b][p][h][d] = 64*16*2*128 floats

__device__ __forceinline__ float lrelu(float z) { return z >= 0.f ? z : NEG_SLOPE * z; }

// ---------------------------------------------------------------------------
// Setup: grid 48 = 3 layers x 16 sub-blocks. LDS-tiled coalesced transpose;
// sub==0 block also computes u vectors (u = a @ W).
__global__ __launch_bounds__(256) void setup_kernel(
    const float* __restrict__ W0, const float* __restrict__ as0, const float* __restrict__ ad0,
    const float* __restrict__ W1, const float* __restrict__ as1, const float* __restrict__ ad1,
    const float* __restrict__ W2, const float* __restrict__ as2, const float* __restrict__ ad2,
    float* __restrict__ ws) {
  __shared__ float tile[8][132];
  const int bid = blockIdx.x;
  const int l = bid >> 4, sub = bid & 15;
  const int tid = threadIdx.x;
  const float* W = (l == 0) ? W0 : (l == 1) ? W1 : W2;
  float* WT = ws + OFF_WT + l * 16384;
  const int e0 = sub * 8;

#pragma unroll
  for (int i = 0; i < 4; ++i) {     // read 8 rows of W, coalesced
    const int idx = i * 256 + tid;
    tile[idx >> 7][idx & 127] = W[(e0 + (idx >> 7)) * 128 + (idx & 127)];
  }
  __syncthreads();
#pragma unroll
  for (int i = 0; i < 4; ++i) {     // write transposed
    const int idx = i * 256 + tid;
    const int d = idx >> 3, j = idx & 7;
    WT[d * 128 + e0 + j] = tile[j][d];
  }
  if (sub == 0) {
    const float* av = (tid < 128) ? ((l == 0) ? as0 : (l == 1) ? as1 : as2)
                                  : ((l == 0) ? ad0 : (l == 1) ? ad1 : ad2);
    const int d = tid & 127;
    float acc = 0.f;
#pragma unroll 8
    for (int e = 0; e < 128; ++e) acc += av[e] * W[e * 128 + d];
    ws[OFF_U + l * 256 + tid] = acc;
  }
}

// ---------------------------------------------------------------------------
// Layer 0: one block per (b, patch p, half h). 512 threads, 128 cols, x kept
// in registers (8 x float4/thread = 32 VGPR). LDS ~15 KB. 2 blocks/CU.
// Output: x~ half-partial (128 floats); feat GEMV deferred to l12.
__global__ __launch_bounds__(512, 4) void l0_kernel(
    const float* __restrict__ x, const int* __restrict__ lengths,
    const float* __restrict__ uvec, float* __restrict__ xt_out) {
  __shared__ float u_sh[256];
  __shared__ float stp[8][256];      // per-wave s (0..127) / t (128..255) partials
  __shared__ float hal[4][128];      // halo per-d products: s@cA,t@cA,s@cB,t@cB
  __shared__ float hred[4][32];
  __shared__ float sF[132], tF[132]; // index k+2, k = col rel c0 (-2..129)
  __shared__ float am1[132], asf[132], ap1[132];
  __shared__ float w_sh[128];

  const int tid  = threadIdx.x;
  const int bid  = blockIdx.x;
  const int b = bid >> 5;
  const int p = (bid >> 1) & 15;
  const int h = bid & 1;
  const int lane = tid & 63;
  const int wave = tid >> 6;
  const int l32  = lane & 31;
  const int hi32 = (lane >> 5) & 1;
  const int c0 = h * 128;

  if (tid < 256) u_sh[tid] = uvec[tid];

  // ---- issue all global loads up front (x stays in registers) ----
  const float* xb = x + ((size_t)b * 128) * 4096 + p * 256 + c0;
  float4 xr[8];
#pragma unroll
  for (int it = 0; it < 8; ++it) {
    const int d = it * 16 + wave * 2 + hi32;
    xr[it] = *(const float4*)(xb + (size_t)d * 4096 + l32 * 4);
  }
  // halo column load (2 cols; grp selects which), threads 0..255 only
  const int grp = (tid >> 7) & 1;
  float hv = 0.f;
  if (tid < 256) {
    const int hc = ((h == 0) ? 128 : 126) + grp;     // absolute col in patch
    hv = x[((size_t)b * 128 + (tid & 127)) * 4096 + p * 256 + hc];
  }
  __syncthreads();   // u_sh ready

  // ---- s,t dot-product partials (fp32, from registers) ----
  float s0 = 0.f, s1 = 0.f, s2 = 0.f, s3 = 0.f;
  float t0 = 0.f, t1 = 0.f, t2 = 0.f, t3 = 0.f;
#pragma unroll
  for (int it = 0; it < 8; ++it) {
    const int d = it * 16 + wave * 2 + hi32;
    const float us = u_sh[d], ud = u_sh[128 + d];
    const float4 v = xr[it];
    s0 += v.x * us; s1 += v.y * us; s2 += v.z * us; s3 += v.w * us;
    t0 += v.x * ud; t1 += v.y * ud; t2 += v.z * ud; t3 += v.w * ud;
  }
  // halo products
  if (tid < 256) {
    const int dh = tid & 127;
    hal[grp * 2 + 0][dh] = hv * u_sh[dh];
    hal[grp * 2 + 1][dh] = hv * u_sh[128 + dh];
  }

  // fold the two 32-lane halves (different d) together
  s0 += __shfl_xor(s0, 32); s1 += __shfl_xor(s1, 32);
  s2 += __shfl_xor(s2, 32); s3 += __shfl_xor(s3, 32);
  t0 += __shfl_xor(t0, 32); t1 += __shfl_xor(t1, 32);
  t2 += __shfl_xor(t2, 32); t3 += __shfl_xor(t3, 32);
  if (hi32 == 0) {
    const int n4 = l32 * 4;
    *(float4*)(&stp[wave][n4])       = make_float4(s0, s1, s2, s3);
    *(float4*)(&stp[wave][128 + n4]) = make_float4(t0, t1, t2, t3);
  }
  __syncthreads();

  if (tid < 256) {   // combine across 8 waves -> sF/tF main (k=0..127 -> idx 2..129)
    const float r = stp[0][tid] + stp[1][tid] + stp[2][tid] + stp[3][tid]
                  + stp[4][tid] + stp[5][tid] + stp[6][tid] + stp[7][tid];
    if (tid < 128) sF[tid + 2] = r; else tF[tid - 126] = r;
  } else if (tid < 384) {   // halo fold stage 1: [4][128] -> [4][32]
    const int q = (tid - 256) >> 5, i = tid & 31;
    hred[q][i] = hal[q][i] + hal[q][32 + i] + hal[q][64 + i] + hal[q][96 + i];
  }
  __syncthreads();

  if (tid < 4) {     // halo fold stage 2 -> scalars into sF/tF extremes
    float a = 0.f;
#pragma unroll
    for (int i = 0; i < 32; ++i) a += hred[tid][i];
    if (h == 0) {    // cA=128 (k=128), cB=129 (k=129)
      if (tid == 0) sF[130] = a;
      else if (tid == 1) tF[130] = a;
      else if (tid == 2) sF[131] = a;
    } else {         // cA=126 (k=-2), cB=127 (k=-1)
      if (tid == 0) sF[0] = a;
      else if (tid == 2) sF[1] = a;
      else if (tid == 3) tF[1] = a;
    }
  }
  __syncthreads();

  const int len = lengths[b];

  if (tid <= 128) {  // attention for dst k in [h?-1:0 .. h?127:128]
    const int k = tid - (h ? 1 : 0);
    const int a = c0 + k;
    const float tj = tF[k + 2];
    const float ls = lrelu(sF[k + 2] + tj);
    const float lm = (a > 0)   ? lrelu(sF[k + 1] + tj) : -1e30f;
    const float lp = (a < 255) ? lrelu(sF[k + 3] + tj) : -1e30f;
    const float mx = fmaxf(ls, fmaxf(lm, lp));
    const float em = (a > 0)   ? __expf(lm - mx) : 0.f;
    const float es = __expf(ls - mx);
    const float ep = (a < 255) ? __expf(lp - mx) : 0.f;
    const float vj = ((p * 256 + a) < len) ? 1.f : 0.f;
    const float sc = vj / (em + es + ep);
    am1[k + 2] = em * sc; asf[k + 2] = es * sc; ap1[k + 2] = ep * sc;
  }
  __syncthreads();

  if (tid < 128) {   // source weights over this block's 128 cols
    const int n = tid;
    const int a = c0 + n;
    float w = asf[n + 2];
    if (a < 255) w += am1[n + 3];
    if (a > 0)   w += ap1[n + 1];
    w_sh[n] = w;
  }
  __syncthreads();

  {   // x~_half[d] = sum over 128 cols of w[n]*x[d][n]; shfl reduce per d
    const float4 wv = *(const float4*)(&w_sh[l32 * 4]);
    float* dst = xt_out + (((size_t)b * 16 + p) * 2 + h) * 128;
#pragma unroll
    for (int it = 0; it < 8; ++it) {
      float a = wv.x * xr[it].x + wv.y * xr[it].y + wv.z * xr[it].z + wv.w * xr[it].w;
      a += __shfl_xor(a, 1);  a += __shfl_xor(a, 2);  a += __shfl_xor(a, 4);
      a += __shfl_xor(a, 8);  a += __shfl_xor(a, 16);
      if (l32 == 0) {
        const int d = it * 16 + wave * 2 + hi32;
        dst[d] = a;
      }
    }
  }
}

// ---------------------------------------------------------------------------
// Fused: feat GEMV (W0) + layer1 + layer2. One block per b, 256 threads.
__global__ __launch_bounds__(256) void l12_kernel(
    const float* __restrict__ xtp, const int* __restrict__ lengths,
    const float* __restrict__ ws,
    const float* __restrict__ b0, const float* __restrict__ b1,
    const float* __restrict__ b2, float* __restrict__ out) {
  __shared__ float xt[16][128];
  __shared__ float pr[2][16][128];
  __shared__ float feat[16][128];
  __shared__ float spt[2][16][16];
  __shared__ float s1[16], t1[16], am[16], asf[16], ap[16], w16[16];
  __shared__ float rc_sh[16];
  __shared__ float x1t[4][128];
  __shared__ float h1[4][128];

  const int tid = threadIdx.x;
  const int b = blockIdx.x;
  const float* WT0 = ws + OFF_WT;
  const float* WT1 = ws + OFF_WT + 16384;
  const float* WT2 = ws + OFF_WT + 32768;
  const float* u1  = ws + OFF_U + 256;
  const int len = lengths[b];

#pragma unroll
  for (int i = 0; i < 8; ++i) {   // combine half-patch partials
    const int pp = i * 2 + (tid >> 7);
    const int d = tid & 127;
    const size_t base = (((size_t)b * 16 + pp) * 2) * 128;
    xt[pp][d] = xtp[base + d] + xtp[base + 128 + d];
  }
  if (tid < 16) {
    const int rem = len - tid * 256;
    const int cnt = rem < 0 ? 0 : (rem > 256 ? 256 : rem);
    rc_sh[tid] = cnt > 0 ? 1.f / (float)cnt : 0.f;
  }
  __syncthreads();

  {   // feat[p][e] = sum_d xt[p][d] * WT0[d*128+e]
    const int e = tid & 127, dhalf = tid >> 7;
    float acc[16];
#pragma unroll
    for (int q = 0; q < 16; ++q) acc[q] = 0.f;
#pragma unroll 4
    for (int k = 0; k < 64; ++k) {
      const int d = dhalf * 64 + k;
      const float wv = WT0[d * 128 + e];
#pragma unroll
      for (int q = 0; q < 16; ++q) acc[q] += xt[q][d] * wv;
    }
#pragma unroll
    for (int q = 0; q < 16; ++q) pr[dhalf][q][e] = acc[q];
  }
  __syncthreads();
  {
    const int e = tid & 127, ph = tid >> 7;
    const float bb = b0[e];
#pragma unroll
    for (int i = 0; i < 8; ++i) {
      const int q = ph * 8 + i;
      const float rcv = rc_sh[q];
      const float f = (pr[0][q][e] + pr[1][q][e]) * rcv + bb;
      feat[q][e] = (rcv == 0.f) ? 0.f : f;
    }
  }
  __syncthreads();

  {   // layer-1 s,t partials
    const int q = tid >> 4, sl = tid & 15;
    float ps = 0.f, pt = 0.f;
#pragma unroll
    for (int k = 0; k < 8; ++k) {
      const int e = sl * 8 + k;
      const float f = feat[q][e];
      ps += f * u1[e];
      pt += f * u1[128 + e];
    }
    spt[0][q][sl] = ps; spt[1][q][sl] = pt;
  }
  __syncthreads();
  if (tid < 32) {
    const int q = tid >> 4, pp = tid & 15;
    float a = 0.f;
#pragma unroll
    for (int i = 0; i < 16; ++i) a += spt[q][pp][i];
    if (q == 0) s1[pp] = a; else t1[pp] = a;
  }
  __syncthreads();
  if (tid < 16) {   // attention within groups of 4
    const int jl = tid & 3;
    const float tj = t1[tid];
    const float ls = lrelu(s1[tid] + tj);
    const float lm = (jl > 0) ? lrelu(s1[tid - 1] + tj) : -1e30f;
    const float lp = (jl < 3) ? lrelu(s1[tid + 1] + tj) : -1e30f;
    const float mx = fmaxf(ls, fmaxf(lm, lp));
    const float em = (jl > 0) ? __expf(lm - mx) : 0.f;
    const float es = __expf(ls - mx);
    const float ep = (jl < 3) ? __expf(lp - mx) : 0.f;
    const float sc = 1.f / (em + es + ep);
    am[tid] = em * sc; asf[tid] = es * sc; ap[tid] = ep * sc;
  }
  __syncthreads();
  if (tid < 16) {
    const int jl = tid & 3;
    float w = asf[tid];
    if (jl < 3) w += am[tid + 1];
    if (jl > 0) w += ap[tid - 1];
    w16[tid] = w;
  }
  __syncthreads();
#pragma unroll
  for (int r = 0; r < 2; ++r) {   // x1t[g][d] = sum_j w*feat
    const int idx = r * 256 + tid;
    const int g = idx >> 7, d = idx & 127;
    x1t[g][d] = w16[g * 4] * feat[g * 4][d] + w16[g * 4 + 1] * feat[g * 4 + 1][d]
              + w16[g * 4 + 2] * feat[g * 4 + 2][d] + w16[g * 4 + 3] * feat[g * 4 + 3][d];
  }
  __syncthreads();
  {   // layer-1 GEMV
    const int e = tid & 127, gh = tid >> 7;
    float a0 = 0.f, a1 = 0.f;
#pragma unroll 8
    for (int d = 0; d < 128; ++d) {
      const float wv = WT1[d * 128 + e];
      a0 += x1t[gh * 2][d] * wv;
      a1 += x1t[gh * 2 + 1][d] * wv;
    }
    h1[gh * 2][e]     = a0 * 0.25f + b1[e];
    h1[gh * 2 + 1][e] = a1 * 0.25f + b1[e];
  }
  __syncthreads();
  {   // layer-2 GEMV + output
    const int e = tid & 127, gh = tid >> 7;
    float a0 = 0.f, a1 = 0.f;
#pragma unroll 8
    for (int d = 0; d < 128; ++d) {
      const float wv = WT2[d * 128 + e];
      a0 += h1[gh * 2][d] * wv;
      a1 += h1[gh * 2 + 1][d] * wv;
    }
    const float bb = b2[e];
    out[((size_t)b * 128 + e) * 4 + gh * 2]     = a0 + bb;
    out[((size_t)b * 128 + e) * 4 + gh * 2 + 1] = a1 + bb;
  }
}

// ---------------------------------------------------------------------------
extern "C" void kernel_launch(void* const* d_in, const int* in_sizes, int n_in,
                              void* d_out, int out_size, void* d_ws, size_t ws_size,
                              hipStream_t stream) {
  (void)in_sizes; (void)n_in; (void)out_size; (void)ws_size;
  const float* x       = (const float*)d_in[0];
  const int*   lengths = (const int*)  d_in[1];
  const float* W0  = (const float*)d_in[2];
  const float* as0 = (const float*)d_in[3];
  const float* ad0 = (const float*)d_in[4];
  const float* b0  = (const float*)d_in[5];
  const float* W1  = (const float*)d_in[6];
  const float* as1 = (const float*)d_in[7];
  const float* ad1 = (const float*)d_in[8];
  const float* b1  = (const float*)d_in[9];
  const float* W2  = (const float*)d_in[10];
  const float* as2 = (const float*)d_in[11];
  const float* ad2 = (const float*)d_in[12];
  const float* b2  = (const float*)d_in[13];
  float* ws  = (float*)d_ws;
  float* out = (float*)d_out;

  setup_kernel<<<48, 256, 0, stream>>>(W0, as0, ad0, W1, as1, ad1, W2, as2, ad2, ws);
  l0_kernel<<<2048, 512, 0, stream>>>(x, lengths, ws + OFF_U, ws + OFF_XT);
  l12_kernel<<<64, 256, 0, stream>>>(ws + OFF_XT, lengths, ws, b0, b1, b2, out);
}